// Round 1
// 605.740 us; speedup vs baseline: 1.0547x; 1.0547x over previous
//
#include <hip/hip_runtime.h>
#include <hip/hip_fp16.h>

#define N_ROWS 8192
#define K_DIM  4096
#define M_DIM  4096
#define NT     (K_DIM / 64)      // 64 K-tiles of BK=64
#define HT_MAX (4 * NT)          // 256 half-tile stage slots

typedef __attribute__((ext_vector_type(8))) _Float16 half8;
typedef __attribute__((ext_vector_type(4))) _Float16 half4v;
typedef __attribute__((ext_vector_type(4))) float    f32x4;

// ---------------------------------------------------------------------------
// Fused prologue.
// Blocks [0, 2048):    wave-per-row: amax -> softplus scale -> int16 fq -> f16
//                      (16 float4 in flight per lane, shfl-only reduce, no LDS)
// Blocks [2048, 6144): weight fold W' = s0*w0 + s1*w1 -> f16, 16 elem/thread
// ---------------------------------------------------------------------------
__global__ __launch_bounds__(256) void prologue_kernel(
    const float* __restrict__ x,  _Float16* __restrict__ xq, float* __restrict__ sx,
    const float* __restrict__ w0, const float* __restrict__ w1,
    const float* __restrict__ s0, const float* __restrict__ s1,
    _Float16* __restrict__ wp)
{
    const int t = threadIdx.x;
    if (blockIdx.x < N_ROWS / 4) {
        // ----- quant path: one wave per row -----
        const int lane = t & 63;
        const int row  = blockIdx.x * 4 + (t >> 6);
        const float4* xr4 = (const float4*)(x + (size_t)row * K_DIM);

        float4 v[16];
        float am = 0.0f;
#pragma unroll
        for (int j = 0; j < 16; ++j) {
            v[j] = xr4[j * 64 + lane];
            am = fmaxf(am, fmaxf(fmaxf(fabsf(v[j].x), fabsf(v[j].y)),
                                 fmaxf(fabsf(v[j].z), fabsf(v[j].w))));
        }
#pragma unroll
        for (int off = 32; off; off >>= 1)
            am = fmaxf(am, __shfl_xor(am, off, 64));

        const float sp    = (am > 20.0f) ? am : log1pf(expf(am));  // softplus
        const float scale = sp * (1.0f / 32767.0f);
        const float inv   = 32767.0f / sp;
        if (lane == 0) sx[row] = scale;

        half4v* out4 = (half4v*)(xq + (size_t)row * K_DIM);
#pragma unroll
        for (int j = 0; j < 16; ++j) {
            half4v h;
            h[0] = (_Float16)fminf(fmaxf(rintf(v[j].x * inv), -32768.0f), 32767.0f);
            h[1] = (_Float16)fminf(fmaxf(rintf(v[j].y * inv), -32768.0f), 32767.0f);
            h[2] = (_Float16)fminf(fmaxf(rintf(v[j].z * inv), -32768.0f), 32767.0f);
            h[3] = (_Float16)fminf(fmaxf(rintf(v[j].w * inv), -32768.0f), 32767.0f);
            out4[j * 64 + lane] = h;
        }
    } else {
        // ----- weight-fold path: 16 elements per thread -----
        const size_t gid  = (size_t)(blockIdx.x - N_ROWS / 4) * 256 + t;
        const size_t base = gid * 16;
        const int    o    = (int)(base >> 12);   // /4096: all 16 elems same row
        const float  a = s0[o], b = s1[o];

        const float4* p0 = (const float4*)(w0 + base);
        const float4* p1 = (const float4*)(w1 + base);
        float4 u[4], w[4];
#pragma unroll
        for (int j = 0; j < 4; ++j) { u[j] = p0[j]; w[j] = p1[j]; }

#pragma unroll
        for (int hv = 0; hv < 2; ++hv) {
            half8 h;
#pragma unroll
            for (int j = 0; j < 2; ++j) {
                const float4 uu = u[hv * 2 + j], ww = w[hv * 2 + j];
                h[j * 4 + 0] = (_Float16)(a * uu.x + b * ww.x);
                h[j * 4 + 1] = (_Float16)(a * uu.y + b * ww.y);
                h[j * 4 + 2] = (_Float16)(a * uu.z + b * ww.z);
                h[j * 4 + 3] = (_Float16)(a * uu.w + b * ww.w);
            }
            *(half8*)(wp + base + hv * 8) = h;
        }
    }
}

// ---------------------------------------------------------------------------
// 256x256 8-phase NT GEMM  out[n,o] = (sum_k Xq[n,k]*Wp[o,k]) * sx[n] + bias[o]
// BK=64, 8 waves (2M x 4N), per-wave 128x64 output (acc[8][4] f32x4).
// 2x double-buffered LDS (128 KiB). Per phase: 12 ds_read_b128 || stage one
// half-tile (2x global_load_lds dwordx4) -> barrier -> lgkmcnt(0) ->
// setprio(1) 16 MFMA setprio(0) -> [vmcnt(4) at phases 4/8] -> barrier.
// LDS chunk swizzle: physical chunk = logical ^ (row&7), applied on the
// GLOBAL source column (DMA dest stays linear) and on the ds_read address.
// Stage order (linear half-tile stream T:{A_lo,B_lo,A_hi,B_hi}) is chosen so
// every stage targets a region dead since a previous barrier; vmcnt(4)+barrier
// at P4/P8 guarantees arrival before the region is re-read. Tail iter gates 0.
// ---------------------------------------------------------------------------
__device__ inline void async_load16(const void* g, void* l)
{
    __builtin_amdgcn_global_load_lds(
        (const __attribute__((address_space(1))) void*)g,
        (__attribute__((address_space(3))) void*)l, 16, 0, 0);
}

#define PHASE(BUF, QM, QN, HT, GATE)                                          \
    {                                                                         \
        half8 af[4][2], bf[2][2];                                             \
        _Pragma("unroll")                                                     \
        for (int i = 0; i < 4; ++i) {                                         \
            const int r = wm * 128 + (QM) * 64 + i * 16 + fr;                 \
            _Pragma("unroll")                                                 \
            for (int ks = 0; ks < 2; ++ks) {                                  \
                const int c = (ks * 4 + fg) ^ (r & 7);                        \
                af[i][ks] = *(const half8*)&As[BUF][r * 64 + c * 8];          \
            }                                                                 \
        }                                                                     \
        _Pragma("unroll")                                                     \
        for (int j = 0; j < 2; ++j) {                                         \
            const int r = wn * 64 + (QN) * 32 + j * 16 + fr;                  \
            _Pragma("unroll")                                                 \
            for (int ks = 0; ks < 2; ++ks) {                                  \
                const int c = (ks * 4 + fg) ^ (r & 7);                        \
                bf[j][ks] = *(const half8*)&Bs[BUF][r * 64 + c * 8];          \
            }                                                                 \
        }                                                                     \
        stage(HT);                                                            \
        __builtin_amdgcn_s_barrier();                                         \
        asm volatile("" ::: "memory");                                        \
        asm volatile("s_waitcnt lgkmcnt(0)" ::: "memory");                    \
        __builtin_amdgcn_sched_barrier(0);                                    \
        __builtin_amdgcn_s_setprio(1);                                        \
        _Pragma("unroll")                                                     \
        for (int ks = 0; ks < 2; ++ks)                                        \
            _Pragma("unroll")                                                 \
            for (int i = 0; i < 4; ++i)                                       \
                _Pragma("unroll")                                             \
                for (int j = 0; j < 2; ++j)                                   \
                    acc[(QM) * 4 + i][(QN) * 2 + j] =                         \
                        __builtin_amdgcn_mfma_f32_16x16x32_f16(               \
                            af[i][ks], bf[j][ks],                             \
                            acc[(QM) * 4 + i][(QN) * 2 + j], 0, 0, 0);        \
        __builtin_amdgcn_s_setprio(0);                                        \
        if ((GATE) == 0)                                                      \
            asm volatile("s_waitcnt vmcnt(0)" ::: "memory");                  \
        else if ((GATE) > 0)                                                  \
            asm volatile("s_waitcnt vmcnt(4)" ::: "memory");                  \
        __builtin_amdgcn_s_barrier();                                         \
        asm volatile("" ::: "memory");                                        \
    }

__global__ __launch_bounds__(512, 2) void gemm_kernel(
    const _Float16* __restrict__ A,   // [N, K]
    const _Float16* __restrict__ B,   // [M, K]
    const float* __restrict__ sx,     // [N]
    const float* __restrict__ bias,   // [M]
    float* __restrict__ out)          // [N, M]
{
    __shared__ __align__(16) _Float16 As[2][256 * 64];
    __shared__ __align__(16) _Float16 Bs[2][256 * 64];

    const int t    = threadIdx.x;
    const int lane = t & 63;
    const int wave = t >> 6;
    const int wm   = wave >> 2;       // 0..1  (M half of block)
    const int wn   = wave & 3;        // 0..3  (N quarter of block)

    // XCD-aware swizzle (512 blocks, 8 XCDs -> 64 contiguous per XCD) then
    // 8x8 supertile over the 32(n) x 16(m) tile grid.
    const int b2  = (blockIdx.x & 7) * 64 + (blockIdx.x >> 3);
    const int sup = b2 >> 6;
    const int loc = b2 & 63;
    const int tm  = (sup & 1) * 8 + (loc & 7);
    const int tn  = (sup >> 1) * 8 + (loc >> 3);
    const int n0  = tn * 256;
    const int o0  = tm * 256;

    const int fr = lane & 15;
    const int fg = lane >> 4;

    f32x4 acc[8][4] = {};

    // stage one half-tile (16 KiB = 2 dwordx4 loads/thread), linear LDS dest,
    // XOR-swizzled global source column.
    auto stage = [&](int ht_) {
        if (ht_ >= HT_MAX) return;
        const int Tt  = ht_ >> 2;
        const int prt = ht_ & 3;                // 0:A_lo 1:B_lo 2:A_hi 3:B_hi
        const int kof = Tt * 64;
        _Float16* lbase = (prt & 1) ? &Bs[Tt & 1][0] : &As[Tt & 1][0];
        const _Float16* gbase = (prt & 1) ? B + (size_t)o0 * K_DIM
                                          : A + (size_t)n0 * K_DIM;
#pragma unroll
        for (int l = 0; l < 2; ++l) {
            const int s  = l * 512 + t;
            const int hr = s >> 3;
            const int pc = s & 7;
            int r;
            if (prt & 1) r = ((hr >> 5) << 6) | ((prt & 2) ? 32 : 0) | (hr & 31);
            else         r = ((hr >> 6) << 7) | ((prt & 2) ? 64 : 0) | (hr & 63);
            const int c = pc ^ (r & 7);
            async_load16(gbase + (size_t)r * K_DIM + kof + c * 8,
                         lbase + r * 64 + pc * 8);
        }
    };

    // prologue: tile0 {A_lo,B_lo,A_hi,B_hi} + tile1 {A_lo,B_lo} = 12 loads;
    // vmcnt(4) -> tile0's 8 loads landed.
#pragma unroll
    for (int h = 0; h < 6; ++h) stage(h);
    asm volatile("s_waitcnt vmcnt(4)" ::: "memory");
    __builtin_amdgcn_s_barrier();
    asm volatile("" ::: "memory");

    int ht = 6;
#pragma unroll 1
    for (int it = 0; it < NT / 2; ++it) {
        const int g = (it == NT / 2 - 1) ? 0 : 4;
        PHASE(0, 0, 0, ht + 0, -1)   // reads A_lo,B_lo | stages buf1.A_hi
        PHASE(0, 0, 1, ht + 1, -1)   // reads A_lo,B_hi | stages buf1.B_hi
        PHASE(0, 1, 0, ht + 2, -1)   // reads A_hi,B_lo | stages buf0'.A_lo
        PHASE(0, 1, 1, ht + 3, g)    // reads A_hi,B_hi | stages buf0'.B_lo | gate
        PHASE(1, 0, 0, ht + 4, -1)   //                 | stages buf0'.A_hi
        PHASE(1, 0, 1, ht + 5, -1)   //                 | stages buf0'.B_hi
        PHASE(1, 1, 0, ht + 6, -1)   //                 | stages buf1'.A_lo
        PHASE(1, 1, 1, ht + 7, g)    //                 | stages buf1'.B_lo | gate
        ht += 8;
    }

    // epilogue: C/D layout col = lane&15 (o), row = (lane>>4)*4 + reg (n)
    float bs[4];
#pragma unroll
    for (int j = 0; j < 4; ++j)
        bs[j] = bias[o0 + wn * 64 + j * 16 + fr];
#pragma unroll
    for (int i = 0; i < 8; ++i) {
        const int nb = n0 + wm * 128 + i * 16 + fg * 4;
#pragma unroll
        for (int r = 0; r < 4; ++r) {
            const float s = sx[nb + r];
            float* orow = out + (size_t)(nb + r) * M_DIM;
#pragma unroll
            for (int j = 0; j < 4; ++j)
                orow[o0 + wn * 64 + j * 16 + fr] = acc[i][j][r] * s + bs[j];
        }
    }
}

// ---------------------------------------------------------------------------
extern "C" void kernel_launch(void* const* d_in, const int* in_sizes, int n_in,
                              void* d_out, int out_size, void* d_ws, size_t ws_size,
                              hipStream_t stream)
{
    const float* x    = (const float*)d_in[0];
    const float* w0   = (const float*)d_in[1];
    const float* w1   = (const float*)d_in[2];
    const float* s0   = (const float*)d_in[3];
    const float* s1   = (const float*)d_in[4];
    const float* bias = (const float*)d_in[5];
    float* out = (float*)d_out;

    char* ws = (char*)d_ws;
    _Float16* xq = (_Float16*)ws;                                   // 64 MiB
    _Float16* wp = (_Float16*)(ws + (size_t)N_ROWS * K_DIM * 2);    // 32 MiB
    float*    sx = (float*)(ws + (size_t)N_ROWS * K_DIM * 2
                               + (size_t)M_DIM * K_DIM * 2);        // 32 KiB

    prologue_kernel<<<N_ROWS / 4 + (M_DIM * K_DIM) / (256 * 16), 256, 0, stream>>>(
        x, xq, sx, w0, w1, s0, s1, wp);

    gemm_kernel<<<(N_ROWS / 256) * (M_DIM / 256), 512, 0, stream>>>(
        xq, wp, sx, bias, out);
}

// Round 2
// 569.220 us; speedup vs baseline: 1.1223x; 1.0642x over previous
//
#include <hip/hip_runtime.h>
#include <hip/hip_fp16.h>

#define N_ROWS 8192
#define K_DIM  4096
#define M_DIM  4096
#define NT     (K_DIM / 64)      // 64 K-tiles of BK=64
#define HT_MAX (4 * NT)          // 256 quarter-tile stage slots

typedef __attribute__((ext_vector_type(8))) _Float16 half8;
typedef __attribute__((ext_vector_type(4))) _Float16 half4v;
typedef __attribute__((ext_vector_type(4))) float    f32x4;

// ---------------------------------------------------------------------------
// Quant: one wave per row: amax -> softplus scale -> int16 fake-quant -> f16.
// 16 float4 in flight per lane, shfl-only reduce, no LDS, no barriers.
// ---------------------------------------------------------------------------
__global__ __launch_bounds__(256) void quant_kernel(
    const float* __restrict__ x, _Float16* __restrict__ xq, float* __restrict__ sx)
{
    const int t    = threadIdx.x;
    const int lane = t & 63;
    const int row  = blockIdx.x * 4 + (t >> 6);
    const float4* xr4 = (const float4*)(x + (size_t)row * K_DIM);

    float4 v[16];
    float am = 0.0f;
#pragma unroll
    for (int j = 0; j < 16; ++j) {
        v[j] = xr4[j * 64 + lane];
        am = fmaxf(am, fmaxf(fmaxf(fabsf(v[j].x), fabsf(v[j].y)),
                             fmaxf(fabsf(v[j].z), fabsf(v[j].w))));
    }
#pragma unroll
    for (int off = 32; off; off >>= 1)
        am = fmaxf(am, __shfl_xor(am, off, 64));

    const float sp    = (am > 20.0f) ? am : log1pf(expf(am));  // softplus
    const float scale = sp * (1.0f / 32767.0f);
    const float inv   = 32767.0f / sp;
    if (lane == 0) sx[row] = scale;

    half4v* out4 = (half4v*)(xq + (size_t)row * K_DIM);
#pragma unroll
    for (int j = 0; j < 16; ++j) {
        half4v h;
        h[0] = (_Float16)fminf(fmaxf(rintf(v[j].x * inv), -32768.0f), 32767.0f);
        h[1] = (_Float16)fminf(fmaxf(rintf(v[j].y * inv), -32768.0f), 32767.0f);
        h[2] = (_Float16)fminf(fmaxf(rintf(v[j].z * inv), -32768.0f), 32767.0f);
        h[3] = (_Float16)fminf(fmaxf(rintf(v[j].w * inv), -32768.0f), 32767.0f);
        out4[j * 64 + lane] = h;
    }
}

// ---------------------------------------------------------------------------
// Weight fold: W' = s0*w0 + s1*w1 -> f16, 16 elements per thread.
// Each block covers exactly one output row (4096 elems) -> s0/s1 uniform.
// ---------------------------------------------------------------------------
__global__ __launch_bounds__(256) void fold_kernel(
    const float* __restrict__ w0, const float* __restrict__ w1,
    const float* __restrict__ s0, const float* __restrict__ s1,
    _Float16* __restrict__ wp)
{
    const size_t gid  = (size_t)blockIdx.x * 256 + threadIdx.x;
    const size_t base = gid * 16;
    const int    o    = (int)(base >> 12);
    const float  a = s0[o], b = s1[o];

    const float4* p0 = (const float4*)(w0 + base);
    const float4* p1 = (const float4*)(w1 + base);
    float4 u[4], w[4];
#pragma unroll
    for (int j = 0; j < 4; ++j) { u[j] = p0[j]; w[j] = p1[j]; }

#pragma unroll
    for (int hv = 0; hv < 2; ++hv) {
        half8 h;
#pragma unroll
        for (int j = 0; j < 2; ++j) {
            const float4 uu = u[hv * 2 + j], ww = w[hv * 2 + j];
            h[j * 4 + 0] = (_Float16)(a * uu.x + b * ww.x);
            h[j * 4 + 1] = (_Float16)(a * uu.y + b * ww.y);
            h[j * 4 + 2] = (_Float16)(a * uu.z + b * ww.z);
            h[j * 4 + 3] = (_Float16)(a * uu.w + b * ww.w);
        }
        *(half8*)(wp + base + hv * 8) = h;
    }
}

// ---------------------------------------------------------------------------
// 256x256 8-phase NT GEMM  out[n,o] = (sum_k Xq[n,k]*Wp[o,k]) * sx[n] + bias[o]
// BK=64, 8 waves (2M x 4N), per-wave 128x64 output (acc[8][4] f32x4 in AGPR).
// Phases split by (k-slice, M-half): per K-tile
//   p1: read B(ks0) all-N (4x b128) + A(M0,ks0) (4x) -> 16 MFMA (M0 x N x ks0)
//   p2: read A(M1,ks0) (4x)                          -> 16 MFMA (M1 x N x ks0)
//   p3: read B(ks1) (4x) + A(M0,ks1) (4x)            -> 16 MFMA
//   p4: read A(M1,ks1) (4x)                          -> 16 MFMA
// = 24 ds_read_b128 / K-tile / wave (the minimum: tile bytes read once),
// half the previous quadrant scheme's 48.
// LDS is k-major: [buf][ks][256 rows][4 chunks of 16B], 64B rows, chunk XOR
// swizzle ^((r>>1)&3) -> uniform 2 lanes/bank (free). DMA dest stays linear
// (byte = wavebase + lane*16); the XOR is applied to the GLOBAL source column
// and to the ds_read address (both-sides rule).
// Stage stream: quarter-tiles {A_k0,B_k0,A_k1,B_k1}; during tile T's 4 phases
// we stage [T+1.A_k1, T+1.B_k1, T+2.A_k0, T+2.B_k0]. vmcnt(4) gates at p4/p8
// only. Re-derived hazards: every stage targets a region whose last ds_read
// finished >=1 barrier earlier; every first-read is covered by the gate two
// half-tiles ahead. Tail iter gates vmcnt(0).
// ---------------------------------------------------------------------------
__device__ inline void async_load16(const void* g, void* l)
{
    __builtin_amdgcn_global_load_lds(
        (const __attribute__((address_space(1))) void*)g,
        (__attribute__((address_space(3))) void*)l, 16, 0, 0);
}

#define PHASE(BUF, KS, MH, RDB, HT, GATE)                                     \
    {                                                                         \
        if (RDB) {                                                            \
            _Pragma("unroll")                                                 \
            for (int j = 0; j < 4; ++j) {                                     \
                const int r = wn * 64 + j * 16 + fr;                          \
                const int c = fg ^ ((r >> 1) & 3);                            \
                bf[j] = *(const half8*)&Bs[BUF][(KS) * 8192 + r * 32 + c * 8];\
            }                                                                 \
        }                                                                     \
        _Pragma("unroll")                                                     \
        for (int i = 0; i < 4; ++i) {                                         \
            const int r = wm * 128 + (MH) * 64 + i * 16 + fr;                 \
            const int c = fg ^ ((r >> 1) & 3);                                \
            af[i] = *(const half8*)&As[BUF][(KS) * 8192 + r * 32 + c * 8];    \
        }                                                                     \
        stage(HT);                                                            \
        __builtin_amdgcn_s_barrier();                                         \
        asm volatile("" ::: "memory");                                        \
        asm volatile("s_waitcnt lgkmcnt(0)" ::: "memory");                    \
        __builtin_amdgcn_sched_barrier(0);                                    \
        __builtin_amdgcn_s_setprio(1);                                        \
        _Pragma("unroll")                                                     \
        for (int i = 0; i < 4; ++i)                                           \
            _Pragma("unroll")                                                 \
            for (int j = 0; j < 4; ++j)                                       \
                acc[(MH) * 4 + i][j] = __builtin_amdgcn_mfma_f32_16x16x32_f16(\
                    af[i], bf[j], acc[(MH) * 4 + i][j], 0, 0, 0);             \
        __builtin_amdgcn_s_setprio(0);                                        \
        if ((GATE) == 0)                                                      \
            asm volatile("s_waitcnt vmcnt(0)" ::: "memory");                  \
        else if ((GATE) > 0)                                                  \
            asm volatile("s_waitcnt vmcnt(4)" ::: "memory");                  \
        __builtin_amdgcn_s_barrier();                                         \
        asm volatile("" ::: "memory");                                        \
    }

__global__ __launch_bounds__(512, 2) void gemm_kernel(
    const _Float16* __restrict__ A,   // [N, K]
    const _Float16* __restrict__ B,   // [M, K]
    const float* __restrict__ sx,     // [N]
    const float* __restrict__ bias,   // [M]
    float* __restrict__ out)          // [N, M]
{
    __shared__ __align__(16) _Float16 As[2][16384];   // [buf][ks*8192 + r*32 + c*8]
    __shared__ __align__(16) _Float16 Bs[2][16384];

    const int t    = threadIdx.x;
    const int lane = t & 63;
    const int wave = t >> 6;
    const int wm   = wave >> 2;       // 0..1  (M half of block)
    const int wn   = wave & 3;        // 0..3  (N quarter of block)

    // XCD-aware swizzle (512 blocks, 8 XCDs -> 64 contiguous per XCD) then
    // 8x8 supertile over the 32(n) x 16(m) tile grid.
    const int b2  = (blockIdx.x & 7) * 64 + (blockIdx.x >> 3);
    const int sup = b2 >> 6;
    const int loc = b2 & 63;
    const int tm  = (sup & 1) * 8 + (loc & 7);
    const int tn  = (sup >> 1) * 8 + (loc >> 3);
    const int n0  = tn * 256;
    const int o0  = tm * 256;

    const int fr = lane & 15;
    const int fg = lane >> 4;

    f32x4 acc[8][4] = {};

    // stage one quarter-tile (16 KiB = 2 dwordx4 loads/thread): k-major LDS,
    // linear dest, XOR-swizzled global source column.
    auto stage = [&](int ht_) {
        if (ht_ >= HT_MAX) return;
        const int Tt  = ht_ >> 2;
        const int prt = ht_ & 3;               // 0:A_k0 1:B_k0 2:A_k1 3:B_k1
        const int ks  = prt >> 1;
        const int kof = Tt * 64 + ks * 32;     // k start (halfs)
        _Float16* lbase = ((prt & 1) ? &Bs[Tt & 1][0] : &As[Tt & 1][0]) + ks * 8192;
        const _Float16* gbase = (prt & 1) ? B + (size_t)o0 * K_DIM
                                          : A + (size_t)n0 * K_DIM;
#pragma unroll
        for (int l = 0; l < 2; ++l) {
            const int s  = l * 512 + t;
            const int r  = s >> 2;             // row 0..255
            const int pc = s & 3;              // LDS chunk (linear dest)
            const int c  = pc ^ ((r >> 1) & 3);// global chunk fetched
            async_load16(gbase + (size_t)r * K_DIM + kof + c * 8,
                         lbase + r * 32 + pc * 8);
        }
    };

    // prologue: tile0 {A_k0,B_k0,A_k1,B_k1} + tile1 {A_k0,B_k0} = 12 loads;
    // vmcnt(4) -> tile0's 8 loads landed.
#pragma unroll
    for (int h = 0; h < 6; ++h) stage(h);
    asm volatile("s_waitcnt vmcnt(4)" ::: "memory");
    __builtin_amdgcn_s_barrier();
    asm volatile("" ::: "memory");

    int ht = 6;
#pragma unroll 1
    for (int it = 0; it < NT / 2; ++it) {
        const int g = (it == NT / 2 - 1) ? 0 : 4;
        half8 af[4], bf[4];
        PHASE(0, 0, 0, 1, ht + 0, -1)   // buf0 ks0 M0 (+B ks0) | stages buf1.A_k1
        PHASE(0, 0, 1, 0, ht + 1, -1)   // buf0 ks0 M1          | stages buf1.B_k1
        PHASE(0, 1, 0, 1, ht + 2, -1)   // buf0 ks1 M0 (+B ks1) | stages buf0'.A_k0
        PHASE(0, 1, 1, 0, ht + 3, g)    // buf0 ks1 M1          | stages buf0'.B_k0 | gate
        PHASE(1, 0, 0, 1, ht + 4, -1)   //                      | stages buf0'.A_k1
        PHASE(1, 0, 1, 0, ht + 5, -1)   //                      | stages buf0'.B_k1
        PHASE(1, 1, 0, 1, ht + 6, -1)   //                      | stages buf1'.A_k0
        PHASE(1, 1, 1, 0, ht + 7, g)    //                      | stages buf1'.B_k0 | gate
        ht += 8;
    }

    // epilogue: C/D layout col = lane&15 (o), row = (lane>>4)*4 + reg (n)
    float bs[4];
#pragma unroll
    for (int j = 0; j < 4; ++j)
        bs[j] = bias[o0 + wn * 64 + j * 16 + fr];
#pragma unroll
    for (int i = 0; i < 8; ++i) {
        const int nb = n0 + wm * 128 + i * 16 + fg * 4;
#pragma unroll
        for (int r = 0; r < 4; ++r) {
            const float s = sx[nb + r];
            float* orow = out + (size_t)(nb + r) * M_DIM;
#pragma unroll
            for (int j = 0; j < 4; ++j)
                orow[o0 + wn * 64 + j * 16 + fr] = acc[i][j][r] * s + bs[j];
        }
    }
}

// ---------------------------------------------------------------------------
extern "C" void kernel_launch(void* const* d_in, const int* in_sizes, int n_in,
                              void* d_out, int out_size, void* d_ws, size_t ws_size,
                              hipStream_t stream)
{
    const float* x    = (const float*)d_in[0];
    const float* w0   = (const float*)d_in[1];
    const float* w1   = (const float*)d_in[2];
    const float* s0   = (const float*)d_in[3];
    const float* s1   = (const float*)d_in[4];
    const float* bias = (const float*)d_in[5];
    float* out = (float*)d_out;

    char* ws = (char*)d_ws;
    _Float16* xq = (_Float16*)ws;                                   // 64 MiB
    _Float16* wp = (_Float16*)(ws + (size_t)N_ROWS * K_DIM * 2);    // 32 MiB
    float*    sx = (float*)(ws + (size_t)N_ROWS * K_DIM * 2
                               + (size_t)M_DIM * K_DIM * 2);        // 32 KiB

    quant_kernel<<<N_ROWS / 4, 256, 0, stream>>>(x, xq, sx);
    fold_kernel<<<(M_DIM * K_DIM) / (256 * 16), 256, 0, stream>>>(w0, w1, s0, s1, wp);

    gemm_kernel<<<(N_ROWS / 256) * (M_DIM / 256), 512, 0, stream>>>(
        xq, wp, sx, bias, out);
}